// Round 1
// baseline (37.239 us; speedup 1.0000x reference)
//
#include <hip/hip_runtime.h>
#include <math.h>

// Problem constants
#define S_SEQ 6
#define H_HEADS 8
#define HD_DIM 64
#define D_MODEL 512

// ws float offsets
#define WS_GW    0        // 512         : (w - mean(w)) * gamma
#define WS_GC    512      // 6*512       : (c_s - mean(c_s)) * gamma
#define WS_STATS 3584     // 13          : vw, cov[6], vc[6]
#define WS_AB    3600     // 3*8*512     : [proj q/k/v][vec A,B0..B5,C][col]
#define WS_D8    15888    // 8*8*8       : per-head q-vec x k-vec dot table (x0.125)
#define WS_VD    16400    // 8*8         : per-head v-vec . Wo_h
// total 16464 floats = 65856 bytes of d_ws

__constant__ float FREQ_BIAS[36] = {
    0.0f, 0.05f, 0.0f, 0.0f, 0.0f, 0.0f,
    0.05f, 0.0f, 0.1f, 0.05f, 0.0f, 0.0f,
    0.0f, 0.1f, 0.0f, 0.1f, 0.0f, 0.0f,
    0.0f, 0.05f, 0.1f, 0.0f, 0.1f, 0.0f,
    0.0f, 0.0f, 0.0f, 0.1f, 0.0f, 0.1f,
    0.0f, 0.0f, 0.0f, 0.0f, 0.1f, 0.0f
};

// Kernel A: LN-folded vectors + stats. One block, 512 threads (d = threadIdx.x).
__global__ __launch_bounds__(512) void kprep(const float* __restrict__ W_in,
                                             const float* __restrict__ b_in,
                                             const float* __restrict__ gamma,
                                             float* __restrict__ ws) {
    const int d = threadIdx.x;
    const int wave = d >> 6, lane = d & 63;
    __shared__ float red[20][8];

    float wd = W_in[d];

    // positional encoding: div = exp(-(2k) ln(1e4)/512); even d -> sin, odd -> cos
    const float k_ln = 0.0179889457300305367f;  // ln(10000)/512
    float dv = expf(-(float)(d & ~1) * k_ln);
    const float freqs[6] = {0.2f, 0.4f, 0.6f, 0.8f, 1.0f, 0.0f};
    float c[6];
    float bi = b_in[d];
    bool odd = (d & 1);
    #pragma unroll
    for (int s = 0; s < 6; ++s) {
        float ph = freqs[s] * dv;
        float pe = odd ? cosf(ph) : sinf(ph);
        c[s] = bi + pe;
    }

    // phase 1: means of w and c_s
    float sums[7];
    sums[0] = wd;
    #pragma unroll
    for (int s = 0; s < 6; ++s) sums[1 + s] = c[s];
    #pragma unroll
    for (int m = 1; m < 64; m <<= 1) {
        #pragma unroll
        for (int k = 0; k < 7; ++k) sums[k] += __shfl_xor(sums[k], m, 64);
    }
    if (lane == 0) {
        #pragma unroll
        for (int k = 0; k < 7; ++k) red[k][wave] = sums[k];
    }
    __syncthreads();
    float mw = 0.f;
    #pragma unroll
    for (int j = 0; j < 8; ++j) mw += red[0][j];
    mw *= (1.0f / 512.0f);
    float mc[6];
    #pragma unroll
    for (int s = 0; s < 6; ++s) {
        float t = 0.f;
        #pragma unroll
        for (int j = 0; j < 8; ++j) t += red[1 + s][j];
        mc[s] = t * (1.0f / 512.0f);
    }
    __syncthreads();

    float hw = wd - mw;
    float hc[6];
    #pragma unroll
    for (int s = 0; s < 6; ++s) hc[s] = c[s] - mc[s];

    // phase 2: second moments (population): vw, cov_s, vc_s
    float moms[13];
    moms[0] = hw * hw;
    #pragma unroll
    for (int s = 0; s < 6; ++s) { moms[1 + s] = hw * hc[s]; moms[7 + s] = hc[s] * hc[s]; }
    #pragma unroll
    for (int m = 1; m < 64; m <<= 1) {
        #pragma unroll
        for (int k = 0; k < 13; ++k) moms[k] += __shfl_xor(moms[k], m, 64);
    }
    if (lane == 0) {
        #pragma unroll
        for (int k = 0; k < 13; ++k) red[k][wave] = moms[k];
    }
    __syncthreads();
    if (d < 13) {
        float t = 0.f;
        #pragma unroll
        for (int j = 0; j < 8; ++j) t += red[d][j];
        ws[WS_STATS + d] = t * (1.0f / 512.0f);
    }

    float g = gamma[d];
    ws[WS_GW + d] = hw * g;
    #pragma unroll
    for (int s = 0; s < 6; ++s) ws[WS_GC + s * 512 + d] = hc[s] * g;
}

// Kernel B: 24 matvecs (3 projections x {A, B0..B5, C}) of 512x512.
// grid 192 blocks x 64 threads; one wave computes 64 output columns.
__global__ __launch_bounds__(64) void kproj(const float* __restrict__ Wq, const float* __restrict__ bq,
                                            const float* __restrict__ Wk, const float* __restrict__ bk,
                                            const float* __restrict__ Wv, const float* __restrict__ bv,
                                            const float* __restrict__ beta,
                                            float* __restrict__ ws) {
    const int wid = blockIdx.x;         // 0..191
    const int p = wid >> 6;             // 0=q 1=k 2=v
    const int rem = wid & 63;
    const int v = rem >> 3;             // 0=A(gw), 1..6=B[s](gc), 7=C(beta)
    const int col = ((rem & 7) << 6) | threadIdx.x;

    const float* W = (p == 0) ? Wq : ((p == 1) ? Wk : Wv);
    const float* bb = (p == 0) ? bq : ((p == 1) ? bk : bv);
    const float* src = (v < 7) ? (ws + 512 * v) : beta;

    float a0 = 0.f, a1 = 0.f, a2 = 0.f, a3 = 0.f;
    #pragma unroll 4
    for (int d = 0; d < 512; d += 4) {
        a0 = fmaf(src[d + 0], W[(d + 0) * 512 + col], a0);
        a1 = fmaf(src[d + 1], W[(d + 1) * 512 + col], a1);
        a2 = fmaf(src[d + 2], W[(d + 2) * 512 + col], a2);
        a3 = fmaf(src[d + 3], W[(d + 3) * 512 + col], a3);
    }
    float acc = (a0 + a1) + (a2 + a3);
    if (v == 7) acc += bb[col];
    ws[WS_AB + ((p << 3) | v) * 512 + col] = acc;
}

// Kernel C: per-head dot tables. One block, 576 threads.
__global__ __launch_bounds__(576) void ktab(const float* __restrict__ Wo,
                                            float* __restrict__ ws) {
    const int t = threadIdx.x;
    if (t < 512) {
        const int h = t >> 6, a = (t >> 3) & 7, b = t & 7;
        const float* qv = ws + WS_AB + a * 512 + h * 64;
        const float* kv = ws + WS_AB + (8 + b) * 512 + h * 64;
        float acc = 0.f;
        #pragma unroll
        for (int c = 0; c < 64; ++c) acc = fmaf(qv[c], kv[c], acc);
        ws[WS_D8 + t] = acc * 0.125f;   // fold hd^-0.5 = 1/8
    } else {
        const int u = t - 512;          // 0..63
        const int h = u >> 3, a = u & 7;
        const float* vv = ws + WS_AB + (16 + a) * 512 + h * 64;
        const float* wo = Wo + h * 64;
        float acc = 0.f;
        #pragma unroll
        for (int c = 0; c < 64; ++c) acc = fmaf(vv[c], wo[c], acc);
        ws[WS_VD + u] = acc;
    }
}

// Main kernel: one thread per (batch, query-row i).
__global__ __launch_bounds__(256) void kmain(const float* __restrict__ x,
                                             const float* __restrict__ ws,
                                             const float* __restrict__ bo,
                                             float* __restrict__ out,
                                             int total) {
    __shared__ float T[589];  // D8[512] | VD[64] | stats[13]
    for (int idx = threadIdx.x; idx < 589; idx += 256) {
        float v;
        if (idx < 512) v = ws[WS_D8 + idx];
        else if (idx < 576) v = ws[WS_VD + (idx - 512)];
        else v = ws[WS_STATS + (idx - 576)];
        T[idx] = v;
    }
    __syncthreads();

    const int g = blockIdx.x * 256 + threadIdx.x;
    if (g >= total) return;
    const unsigned b = (unsigned)g / 6u;
    const int i = g - (int)b * 6;

    const float* D8 = T;
    const float* VD = T + 512;
    const float vw = T[576];
    const float* cov = T + 577;
    const float* vc = T + 583;

    float al[6], r[6], u[6];
    #pragma unroll
    for (int j = 0; j < 6; ++j) {
        float a = x[b * 6u + j];
        al[j] = a;
        float var = fmaf(a, fmaf(a, vw, 2.0f * cov[j]), vc[j]) + 1e-5f;
        r[j] = rsqrtf(var);
        u[j] = a * r[j];
    }

    float bias[6];
    #pragma unroll
    for (int j = 0; j < 6; ++j) bias[j] = FREQ_BIAS[i * 6 + j];

    const float r_i = r[i], u_i = u[i];
    float acc = 0.f;
    float am[6] = {0.f, 0.f, 0.f, 0.f, 0.f, 0.f};

    #pragma unroll
    for (int h = 0; h < 8; ++h) {
        const float* Dh = D8 + h * 64;
        const float* Vh = VD + h * 8;
        const float P1 = Dh[0], P5 = Dh[7], P7 = Dh[56], P9 = Dh[63];
        const float P3i = Dh[(1 + i) * 8], P6i = Dh[(1 + i) * 8 + 7];

        float s[6];
        #pragma unroll
        for (int j = 0; j < 6; ++j) {
            float t1 = fmaf(u[j], P1, fmaf(r[j], Dh[1 + j], P5));          // * u_i
            float t2 = fmaf(u[j], P3i, fmaf(r[j], Dh[(1 + i) * 8 + 1 + j], P6i)); // * r_i
            float t3 = fmaf(u[j], P7, fmaf(r[j], Dh[57 + j], P9));          // * 1
            s[j] = fmaf(u_i, t1, fmaf(r_i, t2, t3)) + bias[j];
        }
        float m = s[0];
        #pragma unroll
        for (int j = 1; j < 6; ++j) m = fmaxf(m, s[j]);
        float e[6], ssum = 0.f;
        #pragma unroll
        for (int j = 0; j < 6; ++j) { e[j] = __expf(s[j] - m); ssum += e[j]; }
        const float inv = 1.0f / ssum;

        const float av = Vh[0], cv = Vh[7];
        float ha = 0.f;
        #pragma unroll
        for (int j = 0; j < 6; ++j) {
            float a = e[j] * inv;
            am[j] += a;
            float vp = fmaf(u[j], av, r[j] * Vh[1 + j]);
            ha = fmaf(a, vp, ha);
        }
        acc += ha + cv;
    }

    out[g] = acc + bo[0] + al[i];
    float* amout = out + total + (size_t)b * 36u + i * 6;
    #pragma unroll
    for (int j = 0; j < 6; ++j) amout[j] = am[j] * 0.125f;
}

extern "C" void kernel_launch(void* const* d_in, const int* in_sizes, int n_in,
                              void* d_out, int out_size, void* d_ws, size_t ws_size,
                              hipStream_t stream) {
    const float* x     = (const float*)d_in[0];
    const float* W_in  = (const float*)d_in[1];
    const float* b_in  = (const float*)d_in[2];
    const float* Wq    = (const float*)d_in[3];
    const float* bq    = (const float*)d_in[4];
    const float* Wk    = (const float*)d_in[5];
    const float* bk    = (const float*)d_in[6];
    const float* Wv    = (const float*)d_in[7];
    const float* bv    = (const float*)d_in[8];
    const float* Wo    = (const float*)d_in[9];
    const float* bo    = (const float*)d_in[10];
    const float* gamma = (const float*)d_in[11];
    const float* beta  = (const float*)d_in[12];
    float* ws  = (float*)d_ws;
    float* out = (float*)d_out;

    const int total = in_sizes[0];  // B*6

    kprep<<<1, 512, 0, stream>>>(W_in, b_in, gamma, ws);
    kproj<<<192, 64, 0, stream>>>(Wq, bq, Wk, bk, Wv, bv, beta, ws);
    ktab<<<1, 576, 0, stream>>>(Wo, ws);
    kmain<<<(total + 255) / 256, 256, 0, stream>>>(x, ws, bo, out, total);
}

// Round 2
// 24.935 us; speedup vs baseline: 1.4935x; 1.4935x over previous
//
#include <hip/hip_runtime.h>
#include <math.h>

// Problem constants
#define S_SEQ 6
#define H_HEADS 8
#define HD_DIM 64
#define D_MODEL 512

// ws float offsets
#define WS_GW    0        // 512         : (w - mean(w)) * gamma
#define WS_GC    512      // 6*512       : (c_s - mean(c_s)) * gamma
#define WS_STATS 3584     // 13          : vw, cov[6], vc[6]
#define WS_AB    3600     // 3*8*512     : [proj q/k/v][vec A,B0..B5,C][col]  (atomic-accumulated)
#define WS_D8    15888    // 8*8*8       : per-head q-vec x k-vec dot table (x0.125)
#define WS_VD    16400    // 8*8         : per-head v-vec . Wo_h
// total 16464 floats = 65856 bytes of d_ws

__constant__ float FREQ_BIAS[36] = {
    0.0f, 0.05f, 0.0f, 0.0f, 0.0f, 0.0f,
    0.05f, 0.0f, 0.1f, 0.05f, 0.0f, 0.0f,
    0.0f, 0.1f, 0.0f, 0.1f, 0.0f, 0.0f,
    0.0f, 0.05f, 0.1f, 0.0f, 0.1f, 0.0f,
    0.0f, 0.0f, 0.0f, 0.1f, 0.0f, 0.1f,
    0.0f, 0.0f, 0.0f, 0.0f, 0.1f, 0.0f
};

// Kernel A: LN-folded vectors + stats + zero the atomic accumulation region.
__global__ __launch_bounds__(512) void kprep(const float* __restrict__ W_in,
                                             const float* __restrict__ b_in,
                                             const float* __restrict__ gamma,
                                             float* __restrict__ ws) {
    const int d = threadIdx.x;
    const int wave = d >> 6, lane = d & 63;
    __shared__ float red[20][8];

    float wd = W_in[d];

    const float k_ln = 0.0179889457300305367f;  // ln(10000)/512
    float dv = expf(-(float)(d & ~1) * k_ln);
    const float freqs[6] = {0.2f, 0.4f, 0.6f, 0.8f, 1.0f, 0.0f};
    float c[6];
    float bi = b_in[d];
    bool odd = (d & 1);
    #pragma unroll
    for (int s = 0; s < 6; ++s) {
        float ph = freqs[s] * dv;
        float pe = odd ? cosf(ph) : sinf(ph);
        c[s] = bi + pe;
    }

    // zero the AB atomic region while waiting on nothing
    #pragma unroll
    for (int k = 0; k < 24; ++k) ws[WS_AB + k * 512 + d] = 0.0f;

    // phase 1: means of w and c_s
    float sums[7];
    sums[0] = wd;
    #pragma unroll
    for (int s = 0; s < 6; ++s) sums[1 + s] = c[s];
    #pragma unroll
    for (int m = 1; m < 64; m <<= 1) {
        #pragma unroll
        for (int k = 0; k < 7; ++k) sums[k] += __shfl_xor(sums[k], m, 64);
    }
    if (lane == 0) {
        #pragma unroll
        for (int k = 0; k < 7; ++k) red[k][wave] = sums[k];
    }
    __syncthreads();
    float mw = 0.f;
    #pragma unroll
    for (int j = 0; j < 8; ++j) mw += red[0][j];
    mw *= (1.0f / 512.0f);
    float mc[6];
    #pragma unroll
    for (int s = 0; s < 6; ++s) {
        float t = 0.f;
        #pragma unroll
        for (int j = 0; j < 8; ++j) t += red[1 + s][j];
        mc[s] = t * (1.0f / 512.0f);
    }
    __syncthreads();

    float hw = wd - mw;
    float hc[6];
    #pragma unroll
    for (int s = 0; s < 6; ++s) hc[s] = c[s] - mc[s];

    float moms[13];
    moms[0] = hw * hw;
    #pragma unroll
    for (int s = 0; s < 6; ++s) { moms[1 + s] = hw * hc[s]; moms[7 + s] = hc[s] * hc[s]; }
    #pragma unroll
    for (int m = 1; m < 64; m <<= 1) {
        #pragma unroll
        for (int k = 0; k < 13; ++k) moms[k] += __shfl_xor(moms[k], m, 64);
    }
    if (lane == 0) {
        #pragma unroll
        for (int k = 0; k < 13; ++k) red[k][wave] = moms[k];
    }
    __syncthreads();
    if (d < 13) {
        float t = 0.f;
        #pragma unroll
        for (int j = 0; j < 8; ++j) t += red[d][j];
        ws[WS_STATS + d] = t * (1.0f / 512.0f);
    }

    float g = gamma[d];
    ws[WS_GW + d] = hw * g;
    #pragma unroll
    for (int s = 0; s < 6; ++s) ws[WS_GC + s * 512 + d] = hc[s] * g;
}

// Kernel B: 24 matvecs, restructured: block = (p, colgroup, chunk).
// Each thread reads W once per element and FMAs into all 8 folded vectors.
// grid 192 blocks x 64 threads.
__global__ __launch_bounds__(64) void kproj(const float* __restrict__ Wq, const float* __restrict__ bq,
                                            const float* __restrict__ Wk, const float* __restrict__ bk,
                                            const float* __restrict__ Wv, const float* __restrict__ bv,
                                            const float* __restrict__ beta,
                                            float* __restrict__ ws) {
    const int bid = blockIdx.x;
    const int chunk = bid & 7;
    const int cg = (bid >> 3) & 7;
    const int p = bid >> 6;             // 0=q 1=k 2=v
    const int lane = threadIdx.x;
    const int col = (cg << 6) | lane;
    const int d0 = chunk << 6;

    const float* W = (p == 0) ? Wq : ((p == 1) ? Wk : Wv);
    const float* bb = (p == 0) ? bq : ((p == 1) ? bk : bv);

    __shared__ float ls[8][64];
    #pragma unroll
    for (int v = 0; v < 7; ++v) ls[v][lane] = ws[512 * v + d0 + lane];
    ls[7][lane] = beta[d0 + lane];
    __syncthreads();

    float acc[8] = {0.f, 0.f, 0.f, 0.f, 0.f, 0.f, 0.f, 0.f};
    #pragma unroll 4
    for (int dt = 0; dt < 64; dt += 4) {
        float wv[4];
        #pragma unroll
        for (int k = 0; k < 4; ++k) wv[k] = W[(d0 + dt + k) * 512 + col];
        #pragma unroll
        for (int v = 0; v < 8; ++v) {
            float4 s = *(const float4*)&ls[v][dt];
            acc[v] = fmaf(wv[0], s.x, acc[v]);
            acc[v] = fmaf(wv[1], s.y, acc[v]);
            acc[v] = fmaf(wv[2], s.z, acc[v]);
            acc[v] = fmaf(wv[3], s.w, acc[v]);
        }
    }
    if (chunk == 0) acc[7] += bb[col];
    #pragma unroll
    for (int v = 0; v < 8; ++v)
        atomicAdd(&ws[WS_AB + ((p << 3) | v) * 512 + col], acc[v]);
}

// Kernel C: per-head dot tables. 8 blocks (one per head) x 64 threads.
__global__ __launch_bounds__(64) void ktab(const float* __restrict__ Wo,
                                           float* __restrict__ ws) {
    const int h = blockIdx.x;
    const int m = threadIdx.x;          // a*8+b
    const int a = m >> 3, b = m & 7;

    const float4* qv = (const float4*)(ws + WS_AB + a * 512 + h * 64);
    const float4* kv = (const float4*)(ws + WS_AB + (8 + b) * 512 + h * 64);
    float acc = 0.f;
    #pragma unroll
    for (int c = 0; c < 16; ++c) {
        float4 q = qv[c], k = kv[c];
        acc = fmaf(q.x, k.x, acc);
        acc = fmaf(q.y, k.y, acc);
        acc = fmaf(q.z, k.z, acc);
        acc = fmaf(q.w, k.w, acc);
    }
    ws[WS_D8 + h * 64 + m] = acc * 0.125f;   // fold hd^-0.5 = 1/8

    if (m < 8) {
        const float4* vv = (const float4*)(ws + WS_AB + (16 + m) * 512 + h * 64);
        const float4* wo = (const float4*)(Wo + h * 64);
        float acc2 = 0.f;
        #pragma unroll
        for (int c = 0; c < 16; ++c) {
            float4 v = vv[c], w = wo[c];
            acc2 = fmaf(v.x, w.x, acc2);
            acc2 = fmaf(v.y, w.y, acc2);
            acc2 = fmaf(v.z, w.z, acc2);
            acc2 = fmaf(v.w, w.w, acc2);
        }
        ws[WS_VD + h * 8 + m] = acc2;
    }
}

// Main kernel: one thread per (batch, query-row i).
__global__ __launch_bounds__(256) void kmain(const float* __restrict__ x,
                                             const float* __restrict__ ws,
                                             const float* __restrict__ bo,
                                             float* __restrict__ out,
                                             int total) {
    __shared__ float T[589];  // D8[512] | VD[64] | stats[13]
    __shared__ float xs[272];
    for (int idx = threadIdx.x; idx < 589; idx += 256) {
        float v;
        if (idx < 512) v = ws[WS_D8 + idx];
        else if (idx < 576) v = ws[WS_VD + (idx - 512)];
        else v = ws[WS_STATS + (idx - 576)];
        T[idx] = v;
    }
    const int base = blockIdx.x * 256 - 5;
    for (int idx = threadIdx.x; idx < 272; idx += 256) {
        int gi = base + idx;
        xs[idx] = (gi >= 0 && gi < total) ? x[gi] : 0.f;
    }
    __syncthreads();

    const int g = blockIdx.x * 256 + threadIdx.x;
    if (g >= total) return;
    const unsigned b = (unsigned)g / 6u;
    const int i = g - (int)b * 6;

    const float* D8 = T;
    const float* VD = T + 512;
    const float vw = T[576];
    const float* cov = T + 577;
    const float* vc = T + 583;

    float al[6], r[6], u[6];
    #pragma unroll
    for (int j = 0; j < 6; ++j) {
        float a = xs[threadIdx.x + 5 - i + j];
        al[j] = a;
        float var = fmaf(a, fmaf(a, vw, 2.0f * cov[j]), vc[j]) + 1e-5f;
        r[j] = rsqrtf(var);
        u[j] = a * r[j];
    }

    float bias[6];
    #pragma unroll
    for (int j = 0; j < 6; ++j) bias[j] = FREQ_BIAS[i * 6 + j];

    const float r_i = r[i], u_i = u[i];
    float acc = 0.f;
    float am[6] = {0.f, 0.f, 0.f, 0.f, 0.f, 0.f};

    #pragma unroll
    for (int h = 0; h < 8; ++h) {
        const float* Dh = D8 + h * 64;
        const float* Vh = VD + h * 8;
        const float P1 = Dh[0], P5 = Dh[7], P7 = Dh[56], P9 = Dh[63];
        const float P3i = Dh[(1 + i) * 8], P6i = Dh[(1 + i) * 8 + 7];

        float s[6];
        #pragma unroll
        for (int j = 0; j < 6; ++j) {
            float t1 = fmaf(u[j], P1, fmaf(r[j], Dh[1 + j], P5));
            float t2 = fmaf(u[j], P3i, fmaf(r[j], Dh[(1 + i) * 8 + 1 + j], P6i));
            float t3 = fmaf(u[j], P7, fmaf(r[j], Dh[57 + j], P9));
            s[j] = fmaf(u_i, t1, fmaf(r_i, t2, t3)) + bias[j];
        }
        float m = s[0];
        #pragma unroll
        for (int j = 1; j < 6; ++j) m = fmaxf(m, s[j]);
        float e[6], ssum = 0.f;
        #pragma unroll
        for (int j = 0; j < 6; ++j) { e[j] = __expf(s[j] - m); ssum += e[j]; }
        const float inv = 1.0f / ssum;

        const float av = Vh[0], cv = Vh[7];
        float ha = 0.f;
        #pragma unroll
        for (int j = 0; j < 6; ++j) {
            float a = e[j] * inv;
            am[j] += a;
            float vp = fmaf(u[j], av, r[j] * Vh[1 + j]);
            ha = fmaf(a, vp, ha);
        }
        acc += ha + cv;
    }

    out[g] = acc + bo[0] + al[i];

    float2* amp = (float2*)(out + total + (size_t)g * 6u);
    amp[0] = make_float2(am[0] * 0.125f, am[1] * 0.125f);
    amp[1] = make_float2(am[2] * 0.125f, am[3] * 0.125f);
    amp[2] = make_float2(am[4] * 0.125f, am[5] * 0.125f);
}

extern "C" void kernel_launch(void* const* d_in, const int* in_sizes, int n_in,
                              void* d_out, int out_size, void* d_ws, size_t ws_size,
                              hipStream_t stream) {
    const float* x     = (const float*)d_in[0];
    const float* W_in  = (const float*)d_in[1];
    const float* b_in  = (const float*)d_in[2];
    const float* Wq    = (const float*)d_in[3];
    const float* bq    = (const float*)d_in[4];
    const float* Wk    = (const float*)d_in[5];
    const float* bk    = (const float*)d_in[6];
    const float* Wv    = (const float*)d_in[7];
    const float* bv    = (const float*)d_in[8];
    const float* Wo    = (const float*)d_in[9];
    const float* bo    = (const float*)d_in[10];
    const float* gamma = (const float*)d_in[11];
    const float* beta  = (const float*)d_in[12];
    float* ws  = (float*)d_ws;
    float* out = (float*)d_out;

    const int total = in_sizes[0];  // B*6

    kprep<<<1, 512, 0, stream>>>(W_in, b_in, gamma, ws);
    kproj<<<192, 64, 0, stream>>>(Wq, bq, Wk, bk, Wv, bv, beta, ws);
    ktab<<<8, 64, 0, stream>>>(Wo, ws);
    kmain<<<(total + 255) / 256, 256, 0, stream>>>(x, ws, bo, out, total);
}

// Round 3
// 24.889 us; speedup vs baseline: 1.4962x; 1.0018x over previous
//
#include <hip/hip_runtime.h>
#include <math.h>

// ws float offsets
#define WS_STATS 3584     // 13    : vw, cov[6], vc[6]
#define WS_AB    3600     // 24*512: [proj q/k/v][vec A,B0..B5,C][col]
#define ABS 516           // padded LDS stride for AB in kmain2

__constant__ float FREQ_BIAS[36] = {
    0.0f, 0.05f, 0.0f, 0.0f, 0.0f, 0.0f,
    0.05f, 0.0f, 0.1f, 0.05f, 0.0f, 0.0f,
    0.0f, 0.1f, 0.0f, 0.1f, 0.0f, 0.0f,
    0.0f, 0.05f, 0.1f, 0.0f, 0.1f, 0.0f,
    0.0f, 0.0f, 0.0f, 0.1f, 0.0f, 0.1f,
    0.0f, 0.0f, 0.0f, 0.0f, 0.1f, 0.0f
};

// Kernel 1: fused LN-fold stats + 24 matvecs.
// grid 24 blocks (p * 8 + colgroup) x 512 threads. No atomics: each block owns
// 64 output columns of one projection and accumulates over all 512 rows.
__global__ __launch_bounds__(512) void kfold(const float* __restrict__ W_in,
                                             const float* __restrict__ b_in,
                                             const float* __restrict__ gamma,
                                             const float* __restrict__ beta,
                                             const float* __restrict__ Wq, const float* __restrict__ bq,
                                             const float* __restrict__ Wk, const float* __restrict__ bk,
                                             const float* __restrict__ Wv, const float* __restrict__ bv,
                                             float* __restrict__ ws) {
    const int bid = blockIdx.x;         // 0..23
    const int cg = bid & 7;             // column group (== head)
    const int p = bid >> 3;             // 0=q 1=k 2=v
    const int d = threadIdx.x;          // 0..511
    const int wave = d >> 6, lane = d & 63;

    __shared__ float red[20][8];
    __shared__ float ls[8][512];        // folded src vectors: gw, gc0..5, beta
    __shared__ float partial[8][8][64]; // [wave][vec][col]

    float wd = W_in[d];

    // positional encoding
    const float k_ln = 0.0179889457300305367f;  // ln(10000)/512
    float dv = expf(-(float)(d & ~1) * k_ln);
    const float freqs[6] = {0.2f, 0.4f, 0.6f, 0.8f, 1.0f, 0.0f};
    float c[6];
    float bi = b_in[d];
    bool odd = (d & 1);
    #pragma unroll
    for (int s = 0; s < 6; ++s) {
        float ph = freqs[s] * dv;
        c[s] = bi + (odd ? cosf(ph) : sinf(ph));
    }

    // phase 1: means of w and c_s
    float sums[7];
    sums[0] = wd;
    #pragma unroll
    for (int s = 0; s < 6; ++s) sums[1 + s] = c[s];
    #pragma unroll
    for (int m = 1; m < 64; m <<= 1) {
        #pragma unroll
        for (int k = 0; k < 7; ++k) sums[k] += __shfl_xor(sums[k], m, 64);
    }
    if (lane == 0) {
        #pragma unroll
        for (int k = 0; k < 7; ++k) red[k][wave] = sums[k];
    }
    __syncthreads();
    float mw = 0.f;
    #pragma unroll
    for (int j = 0; j < 8; ++j) mw += red[0][j];
    mw *= (1.0f / 512.0f);
    float mc[6];
    #pragma unroll
    for (int s = 0; s < 6; ++s) {
        float t = 0.f;
        #pragma unroll
        for (int j = 0; j < 8; ++j) t += red[1 + s][j];
        mc[s] = t * (1.0f / 512.0f);
    }
    __syncthreads();

    float hw = wd - mw;
    float hc[6];
    #pragma unroll
    for (int s = 0; s < 6; ++s) hc[s] = c[s] - mc[s];

    // phase 2: second moments -> stats (only block 0 stores)
    float moms[13];
    moms[0] = hw * hw;
    #pragma unroll
    for (int s = 0; s < 6; ++s) { moms[1 + s] = hw * hc[s]; moms[7 + s] = hc[s] * hc[s]; }
    #pragma unroll
    for (int m = 1; m < 64; m <<= 1) {
        #pragma unroll
        for (int k = 0; k < 13; ++k) moms[k] += __shfl_xor(moms[k], m, 64);
    }
    if (lane == 0) {
        #pragma unroll
        for (int k = 0; k < 13; ++k) red[k][wave] = moms[k];
    }

    // fill folded src vectors
    float g = gamma[d];
    ls[0][d] = hw * g;
    #pragma unroll
    for (int s = 0; s < 6; ++s) ls[1 + s][d] = hc[s] * g;
    ls[7][d] = beta[d];
    __syncthreads();

    if (bid == 0 && d < 13) {
        float t = 0.f;
        #pragma unroll
        for (int j = 0; j < 8; ++j) t += red[d][j];
        ws[WS_STATS + d] = t * (1.0f / 512.0f);
    }

    // matvec: wave w handles rows w*64..w*64+63; lane = col offset
    const float* W = (p == 0) ? Wq : ((p == 1) ? Wk : Wv);
    const float* bb = (p == 0) ? bq : ((p == 1) ? bk : bv);
    const int colbase = cg << 6;

    float acc[8] = {0.f, 0.f, 0.f, 0.f, 0.f, 0.f, 0.f, 0.f};
    const int row0 = wave << 6;
    #pragma unroll 4
    for (int rr = 0; rr < 64; ++rr) {
        const int row = row0 + rr;
        float wv = W[row * 512 + colbase + lane];
        #pragma unroll
        for (int v = 0; v < 8; ++v) acc[v] = fmaf(wv, ls[v][row], acc[v]);
    }
    #pragma unroll
    for (int v = 0; v < 8; ++v) partial[wave][v][lane] = acc[v];
    __syncthreads();

    // reduce 8 wave-partials; thread d -> (vec = d>>6, col = d&63)
    {
        const int v = d >> 6, col = d & 63;
        float t = 0.f;
        #pragma unroll
        for (int w = 0; w < 8; ++w) t += partial[w][v][col];
        if (v == 7) t += bb[colbase + col];
        ws[WS_AB + (p * 8 + v) * 512 + colbase + col] = t;
    }
}

// Kernel 2: fused dot-tables + main attention. grid total/256 x 256 threads.
__global__ __launch_bounds__(256) void kmain2(const float* __restrict__ x,
                                              const float* __restrict__ ws,
                                              const float* __restrict__ Wo,
                                              const float* __restrict__ bo,
                                              float* __restrict__ out,
                                              int total) {
    __shared__ float AB[24 * ABS];   // padded: row v at AB[v*516]
    __shared__ float T[592];         // D8[512] | VD[64] | stats[13]
    __shared__ float xs[272];
    const int tid = threadIdx.x;

    // stage AB (L2-hot, 49KB)
    for (int e = tid; e < 24 * 512; e += 256) {
        const int v = e >> 9, col = e & 511;
        AB[v * ABS + col] = ws[WS_AB + e];
    }
    if (tid < 13) T[576 + tid] = ws[WS_STATS + tid];
    const int base = blockIdx.x * 256 - 5;
    for (int idx = tid; idx < 272; idx += 256) {
        const int gi = base + idx;
        xs[idx] = (gi >= 0 && gi < total) ? x[gi] : 0.f;
    }
    __syncthreads();

    // dot tables: D8[h][a][b] (512 entries, 2/thread), VD[h][a] (64 entries)
    #pragma unroll
    for (int ee = 0; ee < 2; ++ee) {
        const int e = tid + ee * 256;
        const int h = e >> 6, a = (e >> 3) & 7, b = e & 7;
        const float* qv = &AB[a * ABS + h * 64];
        const float* kv = &AB[(8 + b) * ABS + h * 64];
        float acc = 0.f;
        #pragma unroll
        for (int cc = 0; cc < 64; ++cc) acc = fmaf(qv[cc], kv[cc], acc);
        T[e] = acc * 0.125f;   // fold hd^-0.5
    }
    if (tid < 64) {
        const int h = tid >> 3, a = tid & 7;
        const float* vv = &AB[(16 + a) * ABS + h * 64];
        const float* wo = Wo + h * 64;
        float acc = 0.f;
        #pragma unroll
        for (int cc = 0; cc < 64; ++cc) acc = fmaf(vv[cc], wo[cc], acc);
        T[512 + tid] = acc;
    }
    __syncthreads();

    const int g = blockIdx.x * 256 + tid;
    if (g >= total) return;
    const unsigned b = (unsigned)g / 6u;
    const int i = g - (int)b * 6;

    const float* D8 = T;
    const float* VD = T + 512;
    const float vw = T[576];
    const float* cov = T + 577;
    const float* vc = T + 583;

    float al[6], r[6], u[6];
    #pragma unroll
    for (int j = 0; j < 6; ++j) {
        float a = xs[tid + 5 - i + j];
        al[j] = a;
        float var = fmaf(a, fmaf(a, vw, 2.0f * cov[j]), vc[j]) + 1e-5f;
        r[j] = rsqrtf(var);
        u[j] = a * r[j];
    }

    float bias[6];
    #pragma unroll
    for (int j = 0; j < 6; ++j) bias[j] = FREQ_BIAS[i * 6 + j];

    const float r_i = r[i], u_i = u[i];
    float acc = 0.f;
    float am[6] = {0.f, 0.f, 0.f, 0.f, 0.f, 0.f};

    #pragma unroll
    for (int h = 0; h < 8; ++h) {
        const float* Dh = D8 + h * 64;
        const float* Vh = VD + h * 8;
        const float P1 = Dh[0], P5 = Dh[7], P7 = Dh[56], P9 = Dh[63];
        const float P3i = Dh[(1 + i) * 8], P6i = Dh[(1 + i) * 8 + 7];

        float s[6];
        #pragma unroll
        for (int j = 0; j < 6; ++j) {
            float t1 = fmaf(u[j], P1, fmaf(r[j], Dh[1 + j], P5));
            float t2 = fmaf(u[j], P3i, fmaf(r[j], Dh[(1 + i) * 8 + 1 + j], P6i));
            float t3 = fmaf(u[j], P7, fmaf(r[j], Dh[57 + j], P9));
            s[j] = fmaf(u_i, t1, fmaf(r_i, t2, t3)) + bias[j];
        }
        float m = s[0];
        #pragma unroll
        for (int j = 1; j < 6; ++j) m = fmaxf(m, s[j]);
        float e[6], ssum = 0.f;
        #pragma unroll
        for (int j = 0; j < 6; ++j) { e[j] = __expf(s[j] - m); ssum += e[j]; }
        const float inv = 1.0f / ssum;

        const float av = Vh[0], cv = Vh[7];
        float ha = 0.f;
        #pragma unroll
        for (int j = 0; j < 6; ++j) {
            float a = e[j] * inv;
            am[j] += a;
            float vp = fmaf(u[j], av, r[j] * Vh[1 + j]);
            ha = fmaf(a, vp, ha);
        }
        acc += ha + cv;
    }

    out[g] = acc + bo[0] + al[i];

    float2* amp = (float2*)(out + total + (size_t)g * 6u);
    amp[0] = make_float2(am[0] * 0.125f, am[1] * 0.125f);
    amp[1] = make_float2(am[2] * 0.125f, am[3] * 0.125f);
    amp[2] = make_float2(am[4] * 0.125f, am[5] * 0.125f);
}

extern "C" void kernel_launch(void* const* d_in, const int* in_sizes, int n_in,
                              void* d_out, int out_size, void* d_ws, size_t ws_size,
                              hipStream_t stream) {
    const float* x     = (const float*)d_in[0];
    const float* W_in  = (const float*)d_in[1];
    const float* b_in  = (const float*)d_in[2];
    const float* Wq    = (const float*)d_in[3];
    const float* bq    = (const float*)d_in[4];
    const float* Wk    = (const float*)d_in[5];
    const float* bk    = (const float*)d_in[6];
    const float* Wv    = (const float*)d_in[7];
    const float* bv    = (const float*)d_in[8];
    const float* Wo    = (const float*)d_in[9];
    const float* bo    = (const float*)d_in[10];
    const float* gamma = (const float*)d_in[11];
    const float* beta  = (const float*)d_in[12];
    float* ws  = (float*)d_ws;
    float* out = (float*)d_out;

    const int total = in_sizes[0];  // B*6

    kfold<<<24, 512, 0, stream>>>(W_in, b_in, gamma, beta, Wq, bq, Wk, bk, Wv, bv, ws);
    kmain2<<<(total + 255) / 256, 256, 0, stream>>>(x, ws, Wo, bo, out, total);
}